// Round 6
// baseline (205.871 us; speedup 1.0000x reference)
//
#include <hip/hip_runtime.h>
#include <math.h>

// PPO loss with GAE.  B=4096 rows, T=2048 steps, fp32 inputs.
// Inputs: 0 rewards(B,T) 1 values(B,T+1) 2 ref_probs(UNUSED) 3 old_probs(B,T)
//         4 curr_probs(B,T) 5 masks(B,T)
// Output: 4 floats: total, ppo, 0.5*value_loss, 0.01*entropy_loss
//
// R6: single-variable test = fully-coalesced gae loads. Thread tid owns two
// 4-elem chunks: A at [4t,4t+4) and B at [1024+4t, ..). r/m float4 loads are
// lane-CONTIGUOUS (16 lines/instr vs 32 before). v loaded as dwords + LDS
// stage of chunk-head values for the +1 boundary (conflict-free). Block scan
// = two parallel wave-level affine suffix scans (A,B) with cross-wave
// function composition; B's full composition (V1024) feeds A's carry.
// adv layout/bf16/K2/K3/K4 unchanged from R5 (verified absmax 0.0).

#define GAMMA     0.99f
#define LAM       0.95f
#define CLIP_LO   0.8f
#define CLIP_HI   1.2f
#define EPSF      1e-9f

constexpr int BB = 4096;
constexpr int TT = 2048;
constexpr long long NN = (long long)BB * TT;   // 8388608
constexpr int GAE_BLOCKS = BB;                 // 1 row per block
constexpr int PPO_BLOCKS = 2048;

// ws layout:
//  [0,32)          stats: float mean, float inv_std_eps, double sum_adv2
//  [64, 64+32K)    gae partials: 4096 x float2
//  [.., +16K)      ppo partials: 2048 x float2
//  [49216, +16.8M) adv in bf16
struct Stats { float mean; float inv; double sum2; };
static constexpr size_t GAE_PART_OFF = 64;
static constexpr size_t PPO_PART_OFF = GAE_PART_OFF + GAE_BLOCKS * sizeof(float2);
static constexpr size_t ADV_OFF      = PPO_PART_OFF + PPO_BLOCKS * sizeof(float2);

__device__ __forceinline__ unsigned bf16_rne(float x) {
    unsigned u = __float_as_uint(x);
    u += 0x7FFFu + ((u >> 16) & 1u);
    return u >> 16;
}

// ---------------------------------------------------------------- K1: GAE scan
__global__ __launch_bounds__(256, 4) void gae_kernel(
    const float* __restrict__ rewards,
    const float* __restrict__ values,
    const float* __restrict__ masks,
    uint2* __restrict__ advb,          // 4 bf16 per uint2
    float2* __restrict__ partials)
{
    const int row  = blockIdx.x;
    const int tid  = threadIdx.x;
    const int lane = tid & 63;
    const int wave = tid >> 6;

    __shared__ float  lvx[513];        // chunk-head v values + v[2048]
    __shared__ float2 wTa[4], wTb[4];
    __shared__ float  wr1[4], wr2[4];

    const float* rrow = rewards + (size_t)row * TT;
    const float* mrow = masks   + (size_t)row * TT;
    const float* vrow = values  + (size_t)row * (TT + 1);

    // ---- fully coalesced loads: lane-contiguous float4 for r/m ----
    float4 rA = *(const float4*)(rrow + 4 * tid);          // elems 4t..4t+3
    float4 mA = *(const float4*)(mrow + 4 * tid);
    float4 rB = *(const float4*)(rrow + 1024 + 4 * tid);   // elems 1024+4t..
    float4 mB = *(const float4*)(mrow + 1024 + 4 * tid);
    // v rows have stride 2049 -> 16B alignment not guaranteed: dword loads
    float vA[4], vB[4];
#pragma unroll
    for (int j = 0; j < 4; ++j) vA[j] = vrow[4 * tid + j];
#pragma unroll
    for (int j = 0; j < 4; ++j) vB[j] = vrow[1024 + 4 * tid + j];

    // stage chunk-head v's for the +1 boundary (conflict-free, consecutive)
    lvx[tid]       = vA[0];
    lvx[256 + tid] = vB[0];
    if (tid == 255) lvx[512] = vrow[2048];
    __syncthreads();
    const float vA4 = lvx[tid + 1];        // v[4t+4]  (tid=255 -> v[1024]=B0 head)
    const float vB4 = lvx[257 + tid];      // v[1024+4t+4] (tid=255 -> v[2048])

    // ---- per-chunk local reverse affine scan (4 elems) ----
    float laA[4], SA[4], laB[4], SB[4];
    {
        float rr[4] = {rA.x, rA.y, rA.z, rA.w};
        float mm[4] = {mA.x, mA.y, mA.z, mA.w};
        float vn[4] = {vA[1], vA[2], vA[3], vA4};
        float d[4], c[4];
#pragma unroll
        for (int j = 0; j < 4; ++j) {
            d[j] = rr[j] + GAMMA * vn[j] * mm[j] - vA[j];
            c[j] = (GAMMA * LAM) * mm[j];
        }
        laA[3] = d[3]; SA[3] = c[3];
#pragma unroll
        for (int j = 2; j >= 0; --j) { laA[j] = d[j] + c[j] * laA[j + 1]; SA[j] = c[j] * SA[j + 1]; }
    }
    {
        float rr[4] = {rB.x, rB.y, rB.z, rB.w};
        float mm[4] = {mB.x, mB.y, mB.z, mB.w};
        float vn[4] = {vB[1], vB[2], vB[3], vB4};
        float d[4], c[4];
#pragma unroll
        for (int j = 0; j < 4; ++j) {
            d[j] = rr[j] + GAMMA * vn[j] * mm[j] - vB[j];
            c[j] = (GAMMA * LAM) * mm[j];
        }
        laB[3] = d[3]; SB[3] = c[3];
#pragma unroll
        for (int j = 2; j >= 0; --j) { laB[j] = d[j] + c[j] * laB[j + 1]; SB[j] = c[j] * SB[j + 1]; }
    }

    // ---- two parallel wave-level suffix scans of chunk affines ----
    float Aa = SA[0], Ba = laA[0];
    float Ab = SB[0], Bb = laB[0];
#pragma unroll
    for (int d = 1; d < 64; d <<= 1) {
        float A2a = __shfl_down(Aa, d, 64), B2a = __shfl_down(Ba, d, 64);
        float A2b = __shfl_down(Ab, d, 64), B2b = __shfl_down(Bb, d, 64);
        if (lane + d < 64) {
            Ba = Ba + Aa * B2a;  Aa = Aa * A2a;
            Bb = Bb + Ab * B2b;  Ab = Ab * A2b;
        }
    }
    if (lane == 0) { wTa[wave] = make_float2(Aa, Ba); wTb[wave] = make_float2(Ab, Bb); }
    __syncthreads();

    // cross-wave: V1024 = all B waves applied to 0; Cb = B waves after `wave`;
    // Ca = A waves after `wave` applied to V1024
    float V = 0.0f, Cb = 0.0f;
#pragma unroll
    for (int ww = 3; ww >= 0; --ww) {
        if (ww == wave) Cb = V;            // T^B_{wave+1..3}(0)
        V = wTb[ww].y + wTb[ww].x * V;     // after loop: V = V1024
    }
    float Ca = V;
    for (int ww = 3; ww > wave; --ww) Ca = wTa[ww].y + wTa[ww].x * Ca;

    float A1a = __shfl_down(Aa, 1, 64), B1a = __shfl_down(Ba, 1, 64);
    float A1b = __shfl_down(Ab, 1, 64), B1b = __shfl_down(Bb, 1, 64);
    float carA = (lane < 63) ? (B1a + A1a * Ca) : Ca;
    float carB = (lane < 63) ? (B1b + A1b * Cb) : Cb;

    // ---- finals: adv, fp32 sums, bf16 pack, coalesced uint2 stores ----
    float s1 = 0.f, s2 = 0.f;
    unsigned ha[4], hb[4];
#pragma unroll
    for (int j = 0; j < 4; ++j) {
        float a = laA[j] + SA[j] * carA;
        s1 += a; s2 += a * a;
        ha[j] = bf16_rne(a);
        float b = laB[j] + SB[j] * carB;
        s1 += b; s2 += b * b;
        hb[j] = bf16_rne(b);
    }
    uint2 pa = {ha[0] | (ha[1] << 16), ha[2] | (ha[3] << 16)};
    uint2 pb = {hb[0] | (hb[1] << 16), hb[2] | (hb[3] << 16)};
    advb[row * 512 + tid]       = pa;   // elems 4t..4t+3
    advb[row * 512 + 256 + tid] = pb;   // elems 1024+4t..

    // ---- block reduce -> one float2 per block ----
#pragma unroll
    for (int off = 32; off > 0; off >>= 1) {
        s1 += __shfl_down(s1, off, 64);
        s2 += __shfl_down(s2, off, 64);
    }
    if (lane == 0) { wr1[wave] = s1; wr2[wave] = s2; }
    __syncthreads();
    if (tid == 0) {
        float2 p = {wr1[0] + wr1[1] + wr1[2] + wr1[3],
                    wr2[0] + wr2[1] + wr2[2] + wr2[3]};
        partials[row] = p;
    }
}

// ------------------------------------- K2: reduce gae partials -> mean, inv_std
__global__ __launch_bounds__(256) void finalize_stats(
    const float2* __restrict__ gp, Stats* __restrict__ stats)
{
    const int tid = threadIdx.x;
    __shared__ double l1[256], l2[256];
    double s1 = 0.0, s2 = 0.0;
    for (int i = tid; i < GAE_BLOCKS; i += 256) {
        float2 p = gp[i];
        s1 += (double)p.x;
        s2 += (double)p.y;
    }
    l1[tid] = s1; l2[tid] = s2;
    __syncthreads();
    for (int st = 128; st > 0; st >>= 1) {
        if (tid < st) { l1[tid] += l1[tid + st]; l2[tid] += l2[tid + st]; }
        __syncthreads();
    }
    if (tid == 0) {
        double S1 = l1[0], S2 = l2[0];
        double mean = S1 / (double)NN;
        double var  = (S2 - S1 * S1 / (double)NN) / (double)(NN - 1); // ddof=1
        stats->mean = (float)mean;
        stats->inv  = (float)(1.0 / (sqrt(var) + 1e-9));
        stats->sum2 = S2;
    }
}

// ------------------------------------------------- K3: ppo surrogate + entropy
__global__ __launch_bounds__(256, 8) void ppo_kernel(
    const float* __restrict__ adv_bf16,   // raw bf16 pairs, read as uint2
    const float* __restrict__ oldp,
    const float* __restrict__ currp,
    const Stats* __restrict__ stats,
    float2* __restrict__ partials)
{
    const float mean = stats->mean;
    const float inv  = stats->inv;
    const int tid = threadIdx.x;
    const int b   = blockIdx.x;

    const uint2*  a2 = (const uint2*)adv_bf16;   // 4 bf16 per uint2
    const float4* o4 = (const float4*)oldp;
    const float4* c4 = (const float4*)currp;

    uint2  Aq[4]; float4 Of[4], Cf[4];
#pragma unroll
    for (int k = 0; k < 4; ++k) {
        int i = b * 1024 + k * 256 + tid;
        Aq[k] = a2[i]; Of[k] = o4[i]; Cf[k] = c4[i];
    }

    float sm = 0.f, se = 0.f;
#pragma unroll
    for (int k = 0; k < 4; ++k) {
        float av[4] = {__uint_as_float(Aq[k].x << 16),
                       __uint_as_float(Aq[k].x & 0xFFFF0000u),
                       __uint_as_float(Aq[k].y << 16),
                       __uint_as_float(Aq[k].y & 0xFFFF0000u)};
        float ov[4] = {Of[k].x, Of[k].y, Of[k].z, Of[k].w};
        float cv[4] = {Cf[k].x, Cf[k].y, Cf[k].z, Cf[k].w};
#pragma unroll
        for (int j = 0; j < 4; ++j) {
            float an    = (av[j] - mean) * inv;
            float ratio = cv[j] * __builtin_amdgcn_rcpf(ov[j] + EPSF);
            float rc    = fminf(fmaxf(ratio, CLIP_LO), CLIP_HI);
            sm += fminf(ratio * an, rc * an);
            se += cv[j] * __logf(cv[j] + EPSF);
        }
    }

#pragma unroll
    for (int off = 32; off > 0; off >>= 1) {
        sm += __shfl_down(sm, off, 64);
        se += __shfl_down(se, off, 64);
    }
    __shared__ float w1[4], w2[4];
    const int wave = tid >> 6, lane = tid & 63;
    if (lane == 0) { w1[wave] = sm; w2[wave] = se; }
    __syncthreads();
    if (tid == 0) {
        float2 p = {w1[0] + w1[1] + w1[2] + w1[3],
                    w2[0] + w2[1] + w2[2] + w2[3]};
        partials[b] = p;
    }
}

// --------------------------------- K4: reduce ppo partials -> 4 output scalars
__global__ __launch_bounds__(256) void finalize_out(
    const float2* __restrict__ pp,
    const Stats* __restrict__ stats,
    float* __restrict__ out)
{
    const int tid = threadIdx.x;
    __shared__ double l1[256], l2[256];
    double s1 = 0.0, s2 = 0.0;
    for (int i = tid; i < PPO_BLOCKS; i += 256) {
        float2 p = pp[i];
        s1 += (double)p.x;
        s2 += (double)p.y;
    }
    l1[tid] = s1; l2[tid] = s2;
    __syncthreads();
    for (int st = 128; st > 0; st >>= 1) {
        if (tid < st) { l1[tid] += l1[tid + st]; l2[tid] += l2[tid + st]; }
        __syncthreads();
    }
    if (tid == 0) {
        double invN = 1.0 / (double)NN;
        double vl   = 0.5  * (stats->sum2 * invN);   // 0.5 * mean(raw_adv^2)
        double ppo  = -(l1[0] * invN);
        double ent  = -0.01 * (l2[0] * invN);
        out[0] = (float)(ppo + vl + ent);
        out[1] = (float)ppo;
        out[2] = (float)vl;
        out[3] = (float)ent;
    }
}

extern "C" void kernel_launch(void* const* d_in, const int* in_sizes, int n_in,
                              void* d_out, int out_size, void* d_ws, size_t ws_size,
                              hipStream_t stream) {
    const float* rewards = (const float*)d_in[0];
    const float* values  = (const float*)d_in[1];
    // d_in[2] = ref_probs: unused by the reference
    const float* oldp    = (const float*)d_in[3];
    const float* currp   = (const float*)d_in[4];
    const float* masks   = (const float*)d_in[5];

    Stats*  stats = (Stats*)d_ws;
    float2* gaep  = (float2*)((char*)d_ws + GAE_PART_OFF);
    float2* ppop  = (float2*)((char*)d_ws + PPO_PART_OFF);
    uint2*  advb  = (uint2*)((char*)d_ws + ADV_OFF);
    float*  out   = (float*)d_out;

    gae_kernel<<<GAE_BLOCKS, 256, 0, stream>>>(rewards, values, masks, advb, gaep);
    finalize_stats<<<1, 256, 0, stream>>>(gaep, stats);
    ppo_kernel<<<PPO_BLOCKS, 256, 0, stream>>>((const float*)advb, oldp, currp, stats, ppop);
    finalize_out<<<1, 256, 0, stream>>>(ppop, stats, out);
}